// Round 1
// baseline (517.448 us; speedup 1.0000x reference)
//
#include <hip/hip_runtime.h>
#include <hip/hip_bf16.h>

using bf16 = __hip_bfloat16;

constexpr int B_ = 32, S_ = 4096, V_ = 256, E_ = 128, H_ = 256, NM_ = 16;
constexpr int GH = 2 * H_;        // 512
constexpr int NC = 64, L_ = 64;   // chunked scan: 64 chunks of 64 steps

typedef __attribute__((ext_vector_type(8))) short bf16x8;
typedef __attribute__((ext_vector_type(4))) float f32x4;

__device__ __forceinline__ float b2f(unsigned short u) {
  union { float f; unsigned int i; } x; x.i = ((unsigned int)u) << 16; return x.f;
}
__device__ __forceinline__ unsigned short f2b(float f) {
  __hip_bfloat16 h = __float2bfloat16(f);
  return __builtin_bit_cast(unsigned short, h);
}

// one scan step: h_t = a*h_{t-1} + bt;  a = 1-sigmoid(gate), bt = sigmoid(gate)*g(hid)
__device__ __forceinline__ void step_ab(float gate, float hid, float& a, float& bt) {
  float e = __expf(gate);
  a = 1.0f / (1.0f + e);                       // sigmoid(-gate) = 1 - z
  float g = (hid >= 0.0f) ? (hid + 0.5f) : (1.0f / (1.0f + __expf(-hid)));
  bt = (1.0f - a) * g;                         // z * g(hid)
}

// ---------------------------------------------------------------- tables
// T0[v][0:256]=gate, [256:512]=hid, [512:768]=align   (f32)
// Wlb = bf16 copy of Wl [2][512][256]
__global__ __launch_bounds__(256) void build_tables(
    const float* __restrict__ emb, const float* __restrict__ W0,
    const float* __restrict__ b0, const float* __restrict__ Walign,
    const float* __restrict__ Wl, float* __restrict__ T0, bf16* __restrict__ Wlb) {
  const int v = blockIdx.x;
  const int t = threadIdx.x;
  __shared__ float e[E_];
  if (t < E_) e[t] = emb[v * E_ + t];
  __syncthreads();
  for (int j = t; j < 768; j += 256) {
    const float* row;
    float acc;
    if (j < 512) { row = W0 + (size_t)j * E_; acc = b0[j]; }
    else         { row = Walign + (size_t)(j - 512) * E_; acc = 0.0f; }
    #pragma unroll 8
    for (int k = 0; k < E_; ++k) acc += row[k] * e[k];
    T0[(size_t)v * 768 + j] = acc;
  }
  const int gid = v * 256 + t;
  for (int i = gid; i < 2 * GH * H_; i += 256 * 256) Wlb[i] = __float2bfloat16(Wl[i]);
}

// ---------------------------------------------------------------- scan pass A (mid layers)
// block=(chunk c, batch b), 64 threads x 4 channels; computes per-chunk (A,B) composition
__global__ __launch_bounds__(64) void scanA_mid(const bf16* __restrict__ gh, float* __restrict__ cAB) {
  const int b = blockIdx.y, c = blockIdx.x;
  const int t4 = threadIdx.x * 4;
  const unsigned short* p = (const unsigned short*)(gh + ((size_t)b * S_ + (size_t)c * L_) * GH);
  float A0=1,A1=1,A2=1,A3=1, B0=0,B1=0,B2=0,B3=0;
  #pragma unroll 4
  for (int t = 0; t < L_; ++t) {
    ushort4 gu = *(const ushort4*)(p + t4);
    ushort4 hu = *(const ushort4*)(p + H_ + t4);
    float a, bt;
    step_ab(b2f(gu.x), b2f(hu.x), a, bt); A0 = a*A0; B0 = a*B0 + bt;
    step_ab(b2f(gu.y), b2f(hu.y), a, bt); A1 = a*A1; B1 = a*B1 + bt;
    step_ab(b2f(gu.z), b2f(hu.z), a, bt); A2 = a*A2; B2 = a*B2 + bt;
    step_ab(b2f(gu.w), b2f(hu.w), a, bt); A3 = a*A3; B3 = a*B3 + bt;
    p += GH;
  }
  float* o = cAB + (size_t)(b * NC + c) * 2 * H_;
  *(float4*)(o + t4)      = make_float4(A0, A1, A2, A3);
  *(float4*)(o + H_ + t4) = make_float4(B0, B1, B2, B3);
}

__global__ __launch_bounds__(64) void scanA_l0(const int* __restrict__ x, const float* __restrict__ T0,
                                               float* __restrict__ cAB) {
  const int b = blockIdx.y, c = blockIdx.x;
  const int t4 = threadIdx.x * 4;
  const int* xp = x + (size_t)b * S_ + (size_t)c * L_;
  float A0=1,A1=1,A2=1,A3=1, B0=0,B1=0,B2=0,B3=0;
  #pragma unroll 4
  for (int t = 0; t < L_; ++t) {
    const float* tp = T0 + (size_t)xp[t] * 768;
    float4 g4 = *(const float4*)(tp + t4);
    float4 h4 = *(const float4*)(tp + 256 + t4);
    float a, bt;
    step_ab(g4.x, h4.x, a, bt); A0 = a*A0; B0 = a*B0 + bt;
    step_ab(g4.y, h4.y, a, bt); A1 = a*A1; B1 = a*B1 + bt;
    step_ab(g4.z, h4.z, a, bt); A2 = a*A2; B2 = a*B2 + bt;
    step_ab(g4.w, h4.w, a, bt); A3 = a*A3; B3 = a*B3 + bt;
  }
  float* o = cAB + (size_t)(b * NC + c) * 2 * H_;
  *(float4*)(o + t4)      = make_float4(A0, A1, A2, A3);
  *(float4*)(o + H_ + t4) = make_float4(B0, B1, B2, B3);
}

// ---------------------------------------------------------------- scan pass B: chunk-level scan
__global__ __launch_bounds__(256) void scanB(const float* __restrict__ cAB, float* __restrict__ cHin) {
  const int b = blockIdx.x, h = threadIdx.x;
  float hp = 0.5f;  // h_0 = g(0)
  for (int c = 0; c < NC; ++c) {
    cHin[(size_t)(b * NC + c) * H_ + h] = hp;
    const float* pc = cAB + (size_t)(b * NC + c) * 2 * H_;
    hp = pc[h] * hp + pc[H_ + h];
  }
}

// ---------------------------------------------------------------- scan pass C (mid): replay + residual, in-place h
__global__ __launch_bounds__(64) void scanC_mid(const bf16* __restrict__ gh, const float* __restrict__ cHin,
                                                bf16* __restrict__ h) {
  const int b = blockIdx.y, c = blockIdx.x;
  const int t4 = threadIdx.x * 4;
  const unsigned short* p = (const unsigned short*)(gh + ((size_t)b * S_ + (size_t)c * L_) * GH);
  unsigned short* hp = (unsigned short*)(h + ((size_t)b * S_ + (size_t)c * L_) * H_);
  float4 hr = *(const float4*)(cHin + (size_t)(b * NC + c) * H_ + t4);
  #pragma unroll 4
  for (int t = 0; t < L_; ++t) {
    ushort4 gu = *(const ushort4*)(p + t4);
    ushort4 hu = *(const ushort4*)(p + H_ + t4);
    ushort4 ru = *(const ushort4*)(hp + t4);
    float a, bt;
    step_ab(b2f(gu.x), b2f(hu.x), a, bt); hr.x = a*hr.x + bt;
    step_ab(b2f(gu.y), b2f(hu.y), a, bt); hr.y = a*hr.y + bt;
    step_ab(b2f(gu.z), b2f(hu.z), a, bt); hr.z = a*hr.z + bt;
    step_ab(b2f(gu.w), b2f(hu.w), a, bt); hr.w = a*hr.w + bt;
    ushort4 o;
    o.x = f2b(hr.x + b2f(ru.x));
    o.y = f2b(hr.y + b2f(ru.y));
    o.z = f2b(hr.z + b2f(ru.z));
    o.w = f2b(hr.w + b2f(ru.w));
    *(ushort4*)(hp + t4) = o;
    p += GH; hp += H_;
  }
}

__global__ __launch_bounds__(64) void scanC_l0(const int* __restrict__ x, const float* __restrict__ T0,
                                               const float* __restrict__ cHin, bf16* __restrict__ h) {
  const int b = blockIdx.y, c = blockIdx.x;
  const int t4 = threadIdx.x * 4;
  const int* xp = x + (size_t)b * S_ + (size_t)c * L_;
  unsigned short* hp = (unsigned short*)(h + ((size_t)b * S_ + (size_t)c * L_) * H_);
  float4 hr = *(const float4*)(cHin + (size_t)(b * NC + c) * H_ + t4);
  #pragma unroll 4
  for (int t = 0; t < L_; ++t) {
    const float* tp = T0 + (size_t)xp[t] * 768;
    float4 g4 = *(const float4*)(tp + t4);
    float4 h4 = *(const float4*)(tp + 256 + t4);
    float4 r4 = *(const float4*)(tp + 512 + t4);
    float a, bt;
    step_ab(g4.x, h4.x, a, bt); hr.x = a*hr.x + bt;
    step_ab(g4.y, h4.y, a, bt); hr.y = a*hr.y + bt;
    step_ab(g4.z, h4.z, a, bt); hr.z = a*hr.z + bt;
    step_ab(g4.w, h4.w, a, bt); hr.w = a*hr.w + bt;
    ushort4 o;
    o.x = f2b(hr.x + r4.x);
    o.y = f2b(hr.y + r4.y);
    o.z = f2b(hr.z + r4.z);
    o.w = f2b(hr.w + r4.w);
    *(ushort4*)(hp + t4) = o;
    hp += H_;
  }
}

// ---------------------------------------------------------------- GEMM: gh[M,512] = h[M,256] @ W[512,256]^T + bias
// 64x64 tile, full K=256 resident in LDS, XOR-swizzled via pre-swizzled global source.
__global__ __launch_bounds__(256) void gemm_gh(const bf16* __restrict__ Ain,
                                               const bf16* __restrict__ W,
                                               const float* __restrict__ bias,
                                               bf16* __restrict__ C) {
  __shared__ __align__(16) char smem[65536];   // A tile 32KB | B tile 32KB
  const int bid = blockIdx.x;
  // XCD-aware: 8 consecutive blocks on one XCD share the A tile (ntile inner)
  const int X = bid & 7, q = bid >> 3;
  const int mtile = X * 256 + (q >> 3);
  const int ntile = q & 7;
  const int m0 = mtile * 64, n0 = ntile * 64;
  const int tid = threadIdx.x;
  const int lane = tid & 63, wave = tid >> 6;

  const char* Ag = (const char*)(Ain + (size_t)m0 * 256);
  const char* Wg = (const char*)(W + (size_t)n0 * 256);
  #pragma unroll
  for (int it = 0; it < 8; ++it) {
    const int o = it * 4096 + tid * 16;        // linear LDS dest offset
    const int row = o >> 9, bb = o & 511;
    const int src = (row << 9) | (bb ^ ((row & 7) << 4));   // inverse-swizzled source
    char* lbaseA = smem + it * 4096 + wave * 1024;          // wave-uniform base
    __builtin_amdgcn_global_load_lds((const __attribute__((address_space(1))) void*)(Ag + src),
                                     (__attribute__((address_space(3))) void*)lbaseA, 16, 0, 0);
    __builtin_amdgcn_global_load_lds((const __attribute__((address_space(1))) void*)(Wg + src),
                                     (__attribute__((address_space(3))) void*)(lbaseA + 32768), 16, 0, 0);
  }
  __syncthreads();

  const int wr = (wave >> 1) * 32, wc = (wave & 1) * 32;
  const int l15 = lane & 15, lhi = lane >> 4;
  f32x4 acc[2][2] = {};
  #pragma unroll
  for (int kk = 0; kk < 8; ++kk) {
    const int kb = kk * 64 + lhi * 16;
    bf16x8 af[2], bfr[2];
    #pragma unroll
    for (int mi = 0; mi < 2; ++mi) {
      const int r = wr + mi * 16 + l15;
      af[mi] = *(const bf16x8*)(smem + ((r << 9) | (kb ^ ((r & 7) << 4))));
    }
    #pragma unroll
    for (int ni = 0; ni < 2; ++ni) {
      const int r = wc + ni * 16 + l15;
      bfr[ni] = *(const bf16x8*)(smem + 32768 + ((r << 9) | (kb ^ ((r & 7) << 4))));
    }
    #pragma unroll
    for (int mi = 0; mi < 2; ++mi)
      #pragma unroll
      for (int ni = 0; ni < 2; ++ni)
        acc[mi][ni] = __builtin_amdgcn_mfma_f32_16x16x32_bf16(af[mi], bfr[ni], acc[mi][ni], 0, 0, 0);
  }
  // C/D layout: col = lane&15, row = (lane>>4)*4 + j
  #pragma unroll
  for (int ni = 0; ni < 2; ++ni) {
    const int col = n0 + wc + ni * 16 + l15;
    const float bc = bias[col];
    #pragma unroll
    for (int mi = 0; mi < 2; ++mi) {
      #pragma unroll
      for (int j = 0; j < 4; ++j) {
        const int rowm = m0 + wr + mi * 16 + lhi * 4 + j;
        C[(size_t)rowm * GH + col] = __float2bfloat16(acc[mi][ni][j] + bc);
      }
    }
  }
}

// ---------------------------------------------------------------- output logits (last NM positions)
__global__ __launch_bounds__(256) void out_logits(const bf16* __restrict__ h,
                                                  const float* __restrict__ Wout,
                                                  const float* __restrict__ bout,
                                                  float* __restrict__ out) {
  const int r = blockIdx.x;            // b*NM + si
  const int b = r >> 4, si = r & 15;
  const int v = threadIdx.x;
  __shared__ float hs[H_];
  const size_t t = (size_t)b * S_ + (S_ - NM_ + si);
  hs[v] = b2f(((const unsigned short*)h)[t * H_ + v]);
  __syncthreads();
  float acc = bout[v];
  const float4* w4 = (const float4*)(Wout + (size_t)v * H_);
  #pragma unroll 8
  for (int k = 0; k < H_ / 4; ++k) {
    float4 wv = w4[k];
    float4 hv = *(const float4*)(hs + 4 * k);
    acc += wv.x * hv.x + wv.y * hv.y + wv.z * hv.z + wv.w * hv.w;
  }
  out[(size_t)r * V_ + v] = acc;
}

// ----------------------------------------------------------------
extern "C" void kernel_launch(void* const* d_in, const int* in_sizes, int n_in,
                              void* d_out, int out_size, void* d_ws, size_t ws_size,
                              hipStream_t stream) {
  const int*   x      = (const int*)d_in[0];
  const float* emb    = (const float*)d_in[1];
  const float* W0     = (const float*)d_in[2];
  const float* b0     = (const float*)d_in[3];
  const float* Wl     = (const float*)d_in[4];
  const float* bl     = (const float*)d_in[5];
  const float* Walign = (const float*)d_in[6];
  const float* Wout   = (const float*)d_in[7];
  const float* bout   = (const float*)d_in[8];
  (void)in_sizes; (void)n_in; (void)out_size; (void)ws_size;

  char* ws = (char*)d_ws;
  size_t off = 0;
  bf16*  gh   = (bf16*)(ws + off);  off += (size_t)B_ * S_ * GH * 2;     // 134 MB
  bf16*  h    = (bf16*)(ws + off);  off += (size_t)B_ * S_ * H_ * 2;     // 67 MB
  float* cAB  = (float*)(ws + off); off += (size_t)B_ * NC * 2 * H_ * 4; // 4 MB
  float* cHin = (float*)(ws + off); off += (size_t)B_ * NC * H_ * 4;     // 2 MB
  float* T0   = (float*)(ws + off); off += (size_t)V_ * 768 * 4;         // 768 KB
  bf16*  Wlb  = (bf16*)(ws + off);  off += (size_t)2 * GH * H_ * 2;      // 512 KB

  build_tables<<<256, 256, 0, stream>>>(emb, W0, b0, Walign, Wl, T0, Wlb);

  dim3 gscan(NC, B_);
  // layer 0: pure table lookups + chunked scan
  scanA_l0<<<gscan, 64, 0, stream>>>(x, T0, cAB);
  scanB<<<B_, 256, 0, stream>>>(cAB, cHin);
  scanC_l0<<<gscan, 64, 0, stream>>>(x, T0, cHin, h);

  for (int layer = 0; layer < 2; ++layer) {
    gemm_gh<<<16384, 256, 0, stream>>>(h, Wlb + (size_t)layer * GH * H_, bl + layer * GH, gh);
    scanA_mid<<<gscan, 64, 0, stream>>>(gh, cAB);
    scanB<<<B_, 256, 0, stream>>>(cAB, cHin);
    scanC_mid<<<gscan, 64, 0, stream>>>(gh, cHin, h);
  }

  out_logits<<<B_ * NM_, 256, 0, stream>>>(h, Wout, bout, (float*)d_out);
}

// Round 2
// 446.969 us; speedup vs baseline: 1.1577x; 1.1577x over previous
//
#include <hip/hip_runtime.h>
#include <hip/hip_bf16.h>

using bf16 = __hip_bfloat16;

constexpr int B_ = 32, S_ = 4096, V_ = 256, E_ = 128, H_ = 256, NM_ = 16;
constexpr int GH = 2 * H_;        // 512
constexpr int NC = 128, L_ = 32;  // chunked scan: 128 chunks of 32 steps

typedef __attribute__((ext_vector_type(8))) short bf16x8;
typedef __attribute__((ext_vector_type(4))) float f32x4;

__device__ __forceinline__ float b2f(unsigned short u) {
  union { float f; unsigned int i; } x; x.i = ((unsigned int)u) << 16; return x.f;
}
__device__ __forceinline__ unsigned short f2b(float f) {
  __hip_bfloat16 h = __float2bfloat16(f);
  return __builtin_bit_cast(unsigned short, h);
}

// one scan step: h_t = a*h_{t-1} + bt;  a = 1-sigmoid(gate), bt = sigmoid(gate)*g(hid)
__device__ __forceinline__ void step_ab(float gate, float hid, float& a, float& bt) {
  float e = __expf(gate);
  a = 1.0f / (1.0f + e);                       // sigmoid(-gate) = 1 - z
  float g = (hid >= 0.0f) ? (hid + 0.5f) : (1.0f / (1.0f + __expf(-hid)));
  bt = (1.0f - a) * g;                         // z * g(hid)
}

// ---------------------------------------------------------------- tables
// T0[v][0:256]=gate, [256:512]=hid, [512:768]=align   (f32)
// Wpk = Wl packed into MFMA B-fragment order, bf16:
//   frag id fid = layer*16384 + kk*2048 + grp*64 + lane  (kk<8, grp<32, lane<64)
//   holds Wl[layer][grp*16 + (lane&15)][kk*32 + (lane>>4)*8 + e], e=0..7
__global__ __launch_bounds__(256) void build_tables(
    const float* __restrict__ emb, const float* __restrict__ W0,
    const float* __restrict__ b0, const float* __restrict__ Walign,
    const float* __restrict__ Wl, float* __restrict__ T0, bf16* __restrict__ Wpk) {
  const int v = blockIdx.x;
  const int t = threadIdx.x;
  __shared__ float e[E_];
  if (t < E_) e[t] = emb[v * E_ + t];
  __syncthreads();
  for (int j = t; j < 768; j += 256) {
    const float* row;
    float acc;
    if (j < 512) { row = W0 + (size_t)j * E_; acc = b0[j]; }
    else         { row = Walign + (size_t)(j - 512) * E_; acc = 0.0f; }
    #pragma unroll 8
    for (int k = 0; k < E_; ++k) acc += row[k] * e[k];
    T0[(size_t)v * 768 + j] = acc;
  }
  const int fid = v * 256 + t;          // 65536 threads, need 32768 fragments
  if (fid < 32768) {
    const int layer = fid >> 14;
    const int kk   = (fid >> 11) & 7;
    const int grp  = (fid >> 6) & 31;
    const int lane = fid & 63;
    const int row = grp * 16 + (lane & 15);
    const int k0  = kk * 32 + (lane >> 4) * 8;
    const float* src = Wl + (((size_t)layer * 512 + row) * 256 + k0);
    bf16* dst = Wpk + (size_t)fid * 8;
    #pragma unroll
    for (int e2 = 0; e2 < 8; ++e2) dst[e2] = __float2bfloat16(src[e2]);
  }
}

// ---------------------------------------------------------------- scan pass A (mid layers)
// 256-thread block = 4 waves; each wave owns one chunk; 64 lanes x 4 channels
__global__ __launch_bounds__(256) void scanA_mid(const bf16* __restrict__ gh, float* __restrict__ cAB) {
  const int b = blockIdx.y;
  const int wv = threadIdx.x >> 6, lane = threadIdx.x & 63;
  const int c = blockIdx.x * 4 + wv;
  const int t4 = lane * 4;
  const unsigned short* p = (const unsigned short*)(gh + ((size_t)b * S_ + (size_t)c * L_) * GH);
  float A0=1,A1=1,A2=1,A3=1, B0=0,B1=0,B2=0,B3=0;
  #pragma unroll 4
  for (int t = 0; t < L_; ++t) {
    ushort4 gu = *(const ushort4*)(p + t4);
    ushort4 hu = *(const ushort4*)(p + H_ + t4);
    float a, bt;
    step_ab(b2f(gu.x), b2f(hu.x), a, bt); A0 = a*A0; B0 = a*B0 + bt;
    step_ab(b2f(gu.y), b2f(hu.y), a, bt); A1 = a*A1; B1 = a*B1 + bt;
    step_ab(b2f(gu.z), b2f(hu.z), a, bt); A2 = a*A2; B2 = a*B2 + bt;
    step_ab(b2f(gu.w), b2f(hu.w), a, bt); A3 = a*A3; B3 = a*B3 + bt;
    p += GH;
  }
  float* o = cAB + (size_t)(b * NC + c) * 2 * H_;
  *(float4*)(o + t4)      = make_float4(A0, A1, A2, A3);
  *(float4*)(o + H_ + t4) = make_float4(B0, B1, B2, B3);
}

__global__ __launch_bounds__(256) void scanA_l0(const int* __restrict__ x, const float* __restrict__ T0,
                                                float* __restrict__ cAB) {
  const int b = blockIdx.y;
  const int wv = threadIdx.x >> 6, lane = threadIdx.x & 63;
  const int c = blockIdx.x * 4 + wv;
  const int t4 = lane * 4;
  const int* xp = x + (size_t)b * S_ + (size_t)c * L_;
  float A0=1,A1=1,A2=1,A3=1, B0=0,B1=0,B2=0,B3=0;
  #pragma unroll 4
  for (int t = 0; t < L_; ++t) {
    const float* tp = T0 + (size_t)xp[t] * 768;
    float4 g4 = *(const float4*)(tp + t4);
    float4 h4 = *(const float4*)(tp + 256 + t4);
    float a, bt;
    step_ab(g4.x, h4.x, a, bt); A0 = a*A0; B0 = a*B0 + bt;
    step_ab(g4.y, h4.y, a, bt); A1 = a*A1; B1 = a*B1 + bt;
    step_ab(g4.z, h4.z, a, bt); A2 = a*A2; B2 = a*B2 + bt;
    step_ab(g4.w, h4.w, a, bt); A3 = a*A3; B3 = a*B3 + bt;
  }
  float* o = cAB + (size_t)(b * NC + c) * 2 * H_;
  *(float4*)(o + t4)      = make_float4(A0, A1, A2, A3);
  *(float4*)(o + H_ + t4) = make_float4(B0, B1, B2, B3);
}

// ---------------------------------------------------------------- scan pass B: chunk-level scan
__global__ __launch_bounds__(256) void scanB(const float* __restrict__ cAB, float* __restrict__ cHin) {
  const int b = blockIdx.x, h = threadIdx.x;
  float hp = 0.5f;  // h_0 = g(0)
  for (int c = 0; c < NC; ++c) {
    cHin[(size_t)(b * NC + c) * H_ + h] = hp;
    const float* pc = cAB + (size_t)(b * NC + c) * 2 * H_;
    hp = pc[h] * hp + pc[H_ + h];
  }
}

// ---------------------------------------------------------------- scan pass C (mid): replay + residual, in-place h
__global__ __launch_bounds__(256) void scanC_mid(const bf16* __restrict__ gh, const float* __restrict__ cHin,
                                                 bf16* __restrict__ h) {
  const int b = blockIdx.y;
  const int wv = threadIdx.x >> 6, lane = threadIdx.x & 63;
  const int c = blockIdx.x * 4 + wv;
  const int t4 = lane * 4;
  const unsigned short* p = (const unsigned short*)(gh + ((size_t)b * S_ + (size_t)c * L_) * GH);
  unsigned short* hp = (unsigned short*)(h + ((size_t)b * S_ + (size_t)c * L_) * H_);
  float4 hr = *(const float4*)(cHin + (size_t)(b * NC + c) * H_ + t4);
  #pragma unroll 4
  for (int t = 0; t < L_; ++t) {
    ushort4 gu = *(const ushort4*)(p + t4);
    ushort4 hu = *(const ushort4*)(p + H_ + t4);
    ushort4 ru = *(const ushort4*)(hp + t4);
    float a, bt;
    step_ab(b2f(gu.x), b2f(hu.x), a, bt); hr.x = a*hr.x + bt;
    step_ab(b2f(gu.y), b2f(hu.y), a, bt); hr.y = a*hr.y + bt;
    step_ab(b2f(gu.z), b2f(hu.z), a, bt); hr.z = a*hr.z + bt;
    step_ab(b2f(gu.w), b2f(hu.w), a, bt); hr.w = a*hr.w + bt;
    ushort4 o;
    o.x = f2b(hr.x + b2f(ru.x));
    o.y = f2b(hr.y + b2f(ru.y));
    o.z = f2b(hr.z + b2f(ru.z));
    o.w = f2b(hr.w + b2f(ru.w));
    *(ushort4*)(hp + t4) = o;
    p += GH; hp += H_;
  }
}

__global__ __launch_bounds__(256) void scanC_l0(const int* __restrict__ x, const float* __restrict__ T0,
                                                const float* __restrict__ cHin, bf16* __restrict__ h) {
  const int b = blockIdx.y;
  const int wv = threadIdx.x >> 6, lane = threadIdx.x & 63;
  const int c = blockIdx.x * 4 + wv;
  const int t4 = lane * 4;
  const int* xp = x + (size_t)b * S_ + (size_t)c * L_;
  unsigned short* hp = (unsigned short*)(h + ((size_t)b * S_ + (size_t)c * L_) * H_);
  float4 hr = *(const float4*)(cHin + (size_t)(b * NC + c) * H_ + t4);
  #pragma unroll 4
  for (int t = 0; t < L_; ++t) {
    const float* tp = T0 + (size_t)xp[t] * 768;
    float4 g4 = *(const float4*)(tp + t4);
    float4 h4 = *(const float4*)(tp + 256 + t4);
    float4 r4 = *(const float4*)(tp + 512 + t4);
    float a, bt;
    step_ab(g4.x, h4.x, a, bt); hr.x = a*hr.x + bt;
    step_ab(g4.y, h4.y, a, bt); hr.y = a*hr.y + bt;
    step_ab(g4.z, h4.z, a, bt); hr.z = a*hr.z + bt;
    step_ab(g4.w, h4.w, a, bt); hr.w = a*hr.w + bt;
    ushort4 o;
    o.x = f2b(hr.x + r4.x);
    o.y = f2b(hr.y + r4.y);
    o.z = f2b(hr.z + r4.z);
    o.w = f2b(hr.w + r4.w);
    *(ushort4*)(hp + t4) = o;
    hp += H_;
  }
}

// ---------------------------------------------------------------- GEMM: gh[M,512] = h[M,256] @ W[512,256]^T + bias
// 64x64 tile, A-tile (full K=256) in LDS (XOR-swizzled via pre-swizzled source),
// B fragments straight from L2 (pre-packed coalesced), C staged in LDS -> b128 stores.
__global__ __launch_bounds__(256, 4) void gemm_gh(const bf16* __restrict__ Ain,
                                                  const bf16* __restrict__ Wp,
                                                  const float* __restrict__ bias,
                                                  bf16* __restrict__ C) {
  __shared__ __align__(16) char smem[40960];   // A tile 32KB | C staging 8KB
  const int bid = blockIdx.x;
  // XCD-aware: 8 consecutive blocks on one XCD share the A tile (ntile inner)
  const int X = bid & 7, q = bid >> 3;
  const int mtile = X * 256 + (q >> 3);
  const int ntile = q & 7;
  const int m0 = mtile * 64, n0 = ntile * 64;
  const int tid = threadIdx.x;
  const int lane = tid & 63, wave = tid >> 6;

  const char* Ag = (const char*)(Ain + (size_t)m0 * 256);
  #pragma unroll
  for (int it = 0; it < 8; ++it) {
    const int o = it * 4096 + tid * 16;        // linear LDS dest offset
    const int row = o >> 9, bb = o & 511;
    const int src = (row << 9) | (bb ^ ((row & 7) << 4));   // inverse-swizzled source
    char* lbase = smem + it * 4096 + wave * 1024;           // wave-uniform base
    __builtin_amdgcn_global_load_lds((const __attribute__((address_space(1))) void*)(Ag + src),
                                     (__attribute__((address_space(3))) void*)lbase, 16, 0, 0);
  }
  __syncthreads();

  const int wr = (wave >> 1) * 32, wc = (wave & 1) * 32;
  const int l15 = lane & 15, lhi = lane >> 4;
  const int grpB = ntile * 4 + (wave & 1) * 2;              // B row-group base for this wave
  f32x4 acc[2][2] = {};
  #pragma unroll
  for (int kk = 0; kk < 8; ++kk) {
    const int kb = kk * 64 + lhi * 16;
    bf16x8 af[2], bfr[2];
    #pragma unroll
    for (int ni = 0; ni < 2; ++ni)
      bfr[ni] = *(const bf16x8*)(Wp + ((size_t)(kk * 32 + grpB + ni) * 64 + lane) * 8);
    #pragma unroll
    for (int mi = 0; mi < 2; ++mi) {
      const int r = wr + mi * 16 + l15;
      af[mi] = *(const bf16x8*)(smem + ((r << 9) | (kb ^ ((r & 7) << 4))));
    }
    #pragma unroll
    for (int mi = 0; mi < 2; ++mi)
      #pragma unroll
      for (int ni = 0; ni < 2; ++ni)
        acc[mi][ni] = __builtin_amdgcn_mfma_f32_16x16x32_bf16(af[mi], bfr[ni], acc[mi][ni], 0, 0, 0);
  }
  // stage C tile in LDS (bf16, [64][64]), then vectorized stores
  unsigned short* stg = (unsigned short*)(smem + 32768);
  #pragma unroll
  for (int ni = 0; ni < 2; ++ni) {
    const int col = wc + ni * 16 + l15;
    const float bc = bias[n0 + col];
    #pragma unroll
    for (int mi = 0; mi < 2; ++mi) {
      #pragma unroll
      for (int j = 0; j < 4; ++j) {
        const int rowm = wr + mi * 16 + lhi * 4 + j;
        stg[rowm * 64 + col] = f2b(acc[mi][ni][j] + bc);
      }
    }
  }
  __syncthreads();
  #pragma unroll
  for (int i = 0; i < 2; ++i) {
    const int idx = tid + i * 256;             // 512 x 16B chunks
    const int row = idx >> 3, cb = idx & 7;
    bf16x8 vv = *(const bf16x8*)(stg + idx * 8);
    *(bf16x8*)(C + (size_t)(m0 + row) * GH + n0 + cb * 8) = vv;
  }
}

// ---------------------------------------------------------------- output logits (last NM positions)
__global__ __launch_bounds__(256) void out_logits(const bf16* __restrict__ h,
                                                  const float* __restrict__ Wout,
                                                  const float* __restrict__ bout,
                                                  float* __restrict__ out) {
  const int r = blockIdx.x;            // b*NM + si
  const int b = r >> 4, si = r & 15;
  const int v = threadIdx.x;
  __shared__ float hs[H_];
  const size_t t = (size_t)b * S_ + (S_ - NM_ + si);
  hs[v] = b2f(((const unsigned short*)h)[t * H_ + v]);
  __syncthreads();
  float acc = bout[v];
  const float4* w4 = (const float4*)(Wout + (size_t)v * H_);
  #pragma unroll 8
  for (int k = 0; k < H_ / 4; ++k) {
    float4 wv = w4[k];
    float4 hv = *(const float4*)(hs + 4 * k);
    acc += wv.x * hv.x + wv.y * hv.y + wv.z * hv.z + wv.w * hv.w;
  }
  out[(size_t)r * V_ + v] = acc;
}

// ----------------------------------------------------------------
extern "C" void kernel_launch(void* const* d_in, const int* in_sizes, int n_in,
                              void* d_out, int out_size, void* d_ws, size_t ws_size,
                              hipStream_t stream) {
  const int*   x      = (const int*)d_in[0];
  const float* emb    = (const float*)d_in[1];
  const float* W0     = (const float*)d_in[2];
  const float* b0     = (const float*)d_in[3];
  const float* Wl     = (const float*)d_in[4];
  const float* bl     = (const float*)d_in[5];
  const float* Walign = (const float*)d_in[6];
  const float* Wout   = (const float*)d_in[7];
  const float* bout   = (const float*)d_in[8];
  (void)in_sizes; (void)n_in; (void)out_size; (void)ws_size;

  char* ws = (char*)d_ws;
  size_t off = 0;
  bf16*  gh   = (bf16*)(ws + off);  off += (size_t)B_ * S_ * GH * 2;     // 134 MB
  bf16*  h    = (bf16*)(ws + off);  off += (size_t)B_ * S_ * H_ * 2;     // 67 MB
  float* cAB  = (float*)(ws + off); off += (size_t)B_ * NC * 2 * H_ * 4; // 8 MB
  float* cHin = (float*)(ws + off); off += (size_t)B_ * NC * H_ * 4;     // 4 MB
  float* T0   = (float*)(ws + off); off += (size_t)V_ * 768 * 4;         // 768 KB
  bf16*  Wpk  = (bf16*)(ws + off);  off += (size_t)2 * GH * H_ * 2;      // 512 KB

  build_tables<<<256, 256, 0, stream>>>(emb, W0, b0, Walign, Wl, T0, Wpk);

  dim3 gscan(NC / 4, B_);
  // layer 0: pure table lookups + chunked scan
  scanA_l0<<<gscan, 256, 0, stream>>>(x, T0, cAB);
  scanB<<<B_, 256, 0, stream>>>(cAB, cHin);
  scanC_l0<<<gscan, 256, 0, stream>>>(x, T0, cHin, h);

  for (int layer = 0; layer < 2; ++layer) {
    gemm_gh<<<16384, 256, 0, stream>>>(h, Wpk + (size_t)layer * GH * H_, bl + layer * GH, gh);
    scanA_mid<<<gscan, 256, 0, stream>>>(gh, cAB);
    scanB<<<B_, 256, 0, stream>>>(cAB, cHin);
    scanC_mid<<<gscan, 256, 0, stream>>>(gh, cHin, h);
  }

  out_logits<<<B_ * NM_, 256, 0, stream>>>(h, Wout, bout, (float*)d_out);
}

// Round 3
// 308.815 us; speedup vs baseline: 1.6756x; 1.4474x over previous
//
#include <hip/hip_runtime.h>
#include <hip/hip_bf16.h>

using bf16 = __hip_bfloat16;

constexpr int B_ = 32, S_ = 4096, V_ = 256, E_ = 128, H_ = 256, NM_ = 16;
constexpr int GH = 2 * H_;        // 512
constexpr int NC = 128, L_ = 32;  // chunked scan: 128 chunks of 32 steps

typedef __attribute__((ext_vector_type(8))) short bf16x8;
typedef __attribute__((ext_vector_type(4))) float f32x4;

__device__ __forceinline__ float b2f(unsigned short u) {
  union { float f; unsigned int i; } x; x.i = ((unsigned int)u) << 16; return x.f;
}
__device__ __forceinline__ unsigned short f2b(float f) {
  __hip_bfloat16 h = __float2bfloat16(f);
  return __builtin_bit_cast(unsigned short, h);
}

// h_t = a*h_{t-1} + bt;  a = 1-sigmoid(gate) = sigmoid(-gate), bt = sigmoid(gate)*g(hid)
__device__ __forceinline__ void step_ab(float gate, float hid, float& a, float& bt) {
  float e = __expf(gate);
  a = 1.0f / (1.0f + e);
  float g = (hid >= 0.0f) ? (hid + 0.5f) : (1.0f / (1.0f + __expf(-hid)));
  bt = (1.0f - a) * g;
}

// ---------------------------------------------------------------- tables
// T0[v][0:256]=a, [256:512]=bt, [512:768]=align   (f32)
// Wpk = Wl packed into MFMA B-fragment order, bf16:
//   fid = layer*16384 + kk*2048 + grp*64 + lane
//   holds Wl[layer][grp*16 + (lane&15)][kk*32 + (lane>>4)*8 + e], e=0..7
__global__ __launch_bounds__(256) void build_tables(
    const float* __restrict__ emb, const float* __restrict__ W0,
    const float* __restrict__ b0, const float* __restrict__ Walign,
    const float* __restrict__ Wl, float* __restrict__ T0, bf16* __restrict__ Wpk) {
  const int v = blockIdx.x;
  const int t = threadIdx.x;
  __shared__ float e[E_];
  if (t < E_) e[t] = emb[v * E_ + t];
  __syncthreads();
  const float4* w0g = (const float4*)(W0 + (size_t)t * E_);
  const float4* w0h = (const float4*)(W0 + (size_t)(t + 256) * E_);
  const float4* wal = (const float4*)(Walign + (size_t)t * E_);
  float g = b0[t], hd = b0[t + 256], al = 0.0f;
  #pragma unroll 8
  for (int k = 0; k < E_ / 4; ++k) {
    float4 ev = *(const float4*)(e + 4 * k);
    float4 ga = w0g[k]; g  += ga.x * ev.x + ga.y * ev.y + ga.z * ev.z + ga.w * ev.w;
    float4 hb = w0h[k]; hd += hb.x * ev.x + hb.y * ev.y + hb.z * ev.z + hb.w * ev.w;
    float4 aw = wal[k]; al += aw.x * ev.x + aw.y * ev.y + aw.z * ev.z + aw.w * ev.w;
  }
  float a, btv; step_ab(g, hd, a, btv);
  T0[(size_t)v * 768 + t]       = a;
  T0[(size_t)v * 768 + 256 + t] = btv;
  T0[(size_t)v * 768 + 512 + t] = al;

  const int fid = v * 256 + t;          // 65536 threads cover 32768 fragments
  if (fid < 32768) {
    const int layer = fid >> 14;
    const int kk   = (fid >> 11) & 7;
    const int grp  = (fid >> 6) & 31;
    const int lane = fid & 63;
    const int row = grp * 16 + (lane & 15);
    const int k0  = kk * 32 + (lane >> 4) * 8;
    const float* src = Wl + (((size_t)layer * 512 + row) * 256 + k0);
    bf16* dst = Wpk + (size_t)fid * 8;
    #pragma unroll
    for (int e2 = 0; e2 < 8; ++e2) dst[e2] = __float2bfloat16(src[e2]);
  }
}

// ---------------------------------------------------------------- layer-0 scan A (table gathers, a/bt direct)
__global__ __launch_bounds__(256) void scanA_l0(const int* __restrict__ x, const float* __restrict__ T0,
                                                float* __restrict__ cAB) {
  const int b = blockIdx.y;
  const int wv = threadIdx.x >> 6, lane = threadIdx.x & 63;
  const int c = blockIdx.x * 4 + wv;
  const int t4 = lane * 4;
  const int* xp = x + (size_t)b * S_ + (size_t)c * L_;
  float A0=1,A1=1,A2=1,A3=1, B0=0,B1=0,B2=0,B3=0;
  #pragma unroll 4
  for (int t = 0; t < L_; ++t) {
    const float* tp = T0 + (size_t)xp[t] * 768;
    float4 a4 = *(const float4*)(tp + t4);
    float4 b4 = *(const float4*)(tp + 256 + t4);
    A0 = a4.x*A0; B0 = a4.x*B0 + b4.x;
    A1 = a4.y*A1; B1 = a4.y*B1 + b4.y;
    A2 = a4.z*A2; B2 = a4.z*B2 + b4.z;
    A3 = a4.w*A3; B3 = a4.w*B3 + b4.w;
  }
  float* o = cAB + (size_t)(b * NC + c) * 2 * H_;
  *(float4*)(o + t4)      = make_float4(A0, A1, A2, A3);
  *(float4*)(o + H_ + t4) = make_float4(B0, B1, B2, B3);
}

// ---------------------------------------------------------------- scan pass B: chunk-level scan (pipelined loads)
__global__ __launch_bounds__(256) void scanB(const float* __restrict__ cAB, float* __restrict__ cHin) {
  const int b = blockIdx.x, ch = threadIdx.x;
  float hp = 0.5f;  // h_0 = g(0)
  const float* pc = cAB + (size_t)b * NC * 2 * H_ + ch;
  float* out = cHin + (size_t)b * NC * H_ + ch;
  float a0 = pc[0], b0v = pc[H_];
  #pragma unroll 4
  for (int c = 0; c < NC - 1; ++c) {
    const float* pn = pc + 2 * H_;
    float a1 = pn[0], b1 = pn[H_];
    out[(size_t)c * H_] = hp;
    hp = a0 * hp + b0v;
    a0 = a1; b0v = b1; pc = pn;
  }
  out[(size_t)(NC - 1) * H_] = hp;
}

// ---------------------------------------------------------------- layer-0 scan C: replay + align residual
__global__ __launch_bounds__(256) void scanC_l0(const int* __restrict__ x, const float* __restrict__ T0,
                                                const float* __restrict__ cHin, bf16* __restrict__ h) {
  const int b = blockIdx.y;
  const int wv = threadIdx.x >> 6, lane = threadIdx.x & 63;
  const int c = blockIdx.x * 4 + wv;
  const int t4 = lane * 4;
  const int* xp = x + (size_t)b * S_ + (size_t)c * L_;
  unsigned short* hp = (unsigned short*)(h + ((size_t)b * S_ + (size_t)c * L_) * H_);
  float4 hr = *(const float4*)(cHin + (size_t)(b * NC + c) * H_ + t4);
  #pragma unroll 4
  for (int t = 0; t < L_; ++t) {
    const float* tp = T0 + (size_t)xp[t] * 768;
    float4 a4 = *(const float4*)(tp + t4);
    float4 b4 = *(const float4*)(tp + 256 + t4);
    float4 r4 = *(const float4*)(tp + 512 + t4);
    hr.x = a4.x*hr.x + b4.x;
    hr.y = a4.y*hr.y + b4.y;
    hr.z = a4.z*hr.z + b4.z;
    hr.w = a4.w*hr.w + b4.w;
    ushort4 o;
    o.x = f2b(hr.x + r4.x);
    o.y = f2b(hr.y + r4.y);
    o.z = f2b(hr.z + r4.z);
    o.w = f2b(hr.w + r4.w);
    *(ushort4*)(hp + t4) = o;
    hp += H_;
  }
}

// ---------------------------------------------------------------- fused GEMM + scanA (mid layers)
// block = one chunk: 32 timesteps x 512 cols. A-tile 16KB LDS (XOR-swizzled),
// B frags from L2-hot packed W, gh strip staged in LDS -> transform to (a,bt),
// in-block chunk composition -> cAB, then coalesced copy-out (skippable).
__global__ __launch_bounds__(256, 3) void gemm_scanA(
    const bf16* __restrict__ Ain, const bf16* __restrict__ Wp,
    const float* __restrict__ bias, bf16* __restrict__ ghp,
    float* __restrict__ cAB, int cSkip) {
  __shared__ __align__(16) char smem[49152];   // A 16KB | strip staging 32KB
  const int bid = blockIdx.x;
  const int c = bid & (NC - 1), b = bid >> 7;
  const size_t row0 = (size_t)b * S_ + (size_t)c * L_;
  const int tid = threadIdx.x, lane = tid & 63, wave = tid >> 6;

  const char* Ag = (const char*)(Ain + row0 * 256);
  #pragma unroll
  for (int it = 0; it < 4; ++it) {
    const int o = it * 4096 + tid * 16;        // linear LDS dest offset
    const int row = o >> 9, bb = o & 511;
    const int src = (row << 9) | (bb ^ ((row & 7) << 4));   // inverse-swizzled source
    char* lbase = smem + it * 4096 + wave * 1024;           // wave-uniform base
    __builtin_amdgcn_global_load_lds((const __attribute__((address_space(1))) void*)(Ag + src),
                                     (__attribute__((address_space(3))) void*)lbase, 16, 0, 0);
  }
  __syncthreads();

  const int l15 = lane & 15, lhi = lane >> 4;
  f32x4 acc[2][8] = {};
  #pragma unroll
  for (int kk = 0; kk < 8; ++kk) {
    const int kb = kk * 64 + lhi * 16;
    bf16x8 af[2], bfr[8];
    #pragma unroll
    for (int ni = 0; ni < 8; ++ni)
      bfr[ni] = *(const bf16x8*)(Wp + ((size_t)(kk * 32 + wave * 8 + ni) * 64 + lane) * 8);
    #pragma unroll
    for (int mi = 0; mi < 2; ++mi) {
      const int r = mi * 16 + l15;
      af[mi] = *(const bf16x8*)(smem + ((r << 9) | (kb ^ ((r & 7) << 4))));
    }
    #pragma unroll
    for (int mi = 0; mi < 2; ++mi)
      #pragma unroll
      for (int ni = 0; ni < 8; ++ni)
        acc[mi][ni] = __builtin_amdgcn_mfma_f32_16x16x32_bf16(af[mi], bfr[ni], acc[mi][ni], 0, 0, 0);
  }

  // stage raw gate/hid strip [32][512] bf16
  unsigned short* stg = (unsigned short*)(smem + 16384);
  #pragma unroll
  for (int ni = 0; ni < 8; ++ni) {
    const int col = wave * 128 + ni * 16 + l15;
    const float bc = bias[col];
    #pragma unroll
    for (int mi = 0; mi < 2; ++mi)
      #pragma unroll
      for (int j = 0; j < 4; ++j)
        stg[(mi * 16 + lhi * 4 + j) * 512 + col] = f2b(acc[mi][ni][j] + bc);
  }
  __syncthreads();

  // transform (gate,hid)->(a,bt) in place + per-chunk composition; thread=channel
  float Aa = 1.0f, Bb = 0.0f;
  #pragma unroll 4
  for (int t = 0; t < L_; ++t) {
    float gate = b2f(stg[t * 512 + tid]);
    float hid  = b2f(stg[t * 512 + 256 + tid]);
    float a, btv; step_ab(gate, hid, a, btv);
    unsigned short ua = f2b(a), ub = f2b(btv);
    stg[t * 512 + tid] = ua;
    stg[t * 512 + 256 + tid] = ub;
    float ar = b2f(ua), br = b2f(ub);        // use rounded values for consistency with scanC
    Aa = ar * Aa; Bb = ar * Bb + br;
  }
  float* o = cAB + ((size_t)b * NC + c) * 2 * H_;
  o[tid] = Aa; o[H_ + tid] = Bb;
  __syncthreads();

  if (c >= cSkip) {
    bf16* gbase = ghp + row0 * 512;          // 32KB contiguous strip
    #pragma unroll
    for (int i = 0; i < 8; ++i) {
      const int idx = tid + i * 256;
      *(bf16x8*)(gbase + (size_t)idx * 8) = *(const bf16x8*)(stg + idx * 8);
    }
  }
}

// ---------------------------------------------------------------- scan C (mid): pure-FMA replay + residual
__global__ __launch_bounds__(256) void scanC_mid(const bf16* __restrict__ gh, const float* __restrict__ cHin,
                                                 bf16* __restrict__ h, int c0) {
  const int b = blockIdx.y;
  const int wv = threadIdx.x >> 6, lane = threadIdx.x & 63;
  const int c = c0 + blockIdx.x * 4 + wv;
  const int t4 = lane * 4;
  const unsigned short* p = (const unsigned short*)(gh + ((size_t)b * S_ + (size_t)c * L_) * GH);
  unsigned short* hp = (unsigned short*)(h + ((size_t)b * S_ + (size_t)c * L_) * H_);
  float4 hr = *(const float4*)(cHin + (size_t)(b * NC + c) * H_ + t4);
  #pragma unroll 4
  for (int t = 0; t < L_; ++t) {
    ushort4 au = *(const ushort4*)(p + t4);
    ushort4 bu = *(const ushort4*)(p + H_ + t4);
    ushort4 ru = *(const ushort4*)(hp + t4);
    hr.x = b2f(au.x)*hr.x + b2f(bu.x);
    hr.y = b2f(au.y)*hr.y + b2f(bu.y);
    hr.z = b2f(au.z)*hr.z + b2f(bu.z);
    hr.w = b2f(au.w)*hr.w + b2f(bu.w);
    ushort4 o;
    o.x = f2b(hr.x + b2f(ru.x));
    o.y = f2b(hr.y + b2f(ru.y));
    o.z = f2b(hr.z + b2f(ru.z));
    o.w = f2b(hr.w + b2f(ru.w));
    *(ushort4*)(hp + t4) = o;
    p += GH; hp += H_;
  }
}

// ---------------------------------------------------------------- output logits (last NM positions)
__global__ __launch_bounds__(256) void out_logits(const bf16* __restrict__ h,
                                                  const float* __restrict__ Wout,
                                                  const float* __restrict__ bout,
                                                  float* __restrict__ out) {
  const int r = blockIdx.x;            // b*NM + si
  const int b = r >> 4, si = r & 15;
  const int v = threadIdx.x;
  __shared__ float hs[H_];
  const size_t t = (size_t)b * S_ + (S_ - NM_ + si);
  hs[v] = b2f(((const unsigned short*)h)[t * H_ + v]);
  __syncthreads();
  float acc = bout[v];
  const float4* w4 = (const float4*)(Wout + (size_t)v * H_);
  #pragma unroll 8
  for (int k = 0; k < H_ / 4; ++k) {
    float4 wv = w4[k];
    float4 hv = *(const float4*)(hs + 4 * k);
    acc += wv.x * hv.x + wv.y * hv.y + wv.z * hv.z + wv.w * hv.w;
  }
  out[(size_t)r * V_ + v] = acc;
}

// ----------------------------------------------------------------
extern "C" void kernel_launch(void* const* d_in, const int* in_sizes, int n_in,
                              void* d_out, int out_size, void* d_ws, size_t ws_size,
                              hipStream_t stream) {
  const int*   x      = (const int*)d_in[0];
  const float* emb    = (const float*)d_in[1];
  const float* W0     = (const float*)d_in[2];
  const float* b0     = (const float*)d_in[3];
  const float* Wl     = (const float*)d_in[4];
  const float* bl     = (const float*)d_in[5];
  const float* Walign = (const float*)d_in[6];
  const float* Wout   = (const float*)d_in[7];
  const float* bout   = (const float*)d_in[8];
  (void)in_sizes; (void)n_in; (void)out_size; (void)ws_size;

  char* ws = (char*)d_ws;
  size_t off = 0;
  bf16*  gh   = (bf16*)(ws + off);  off += (size_t)B_ * S_ * GH * 2;     // 134 MB (a,bt)
  bf16*  h    = (bf16*)(ws + off);  off += (size_t)B_ * S_ * H_ * 2;     // 67 MB
  float* cAB  = (float*)(ws + off); off += (size_t)B_ * NC * 2 * H_ * 4; // 8 MB
  float* cHin = (float*)(ws + off); off += (size_t)B_ * NC * H_ * 4;     // 4 MB
  float* T0   = (float*)(ws + off); off += (size_t)V_ * 768 * 4;         // 768 KB
  bf16*  Wpk  = (bf16*)(ws + off);  off += (size_t)2 * GH * H_ * 2;      // 512 KB

  build_tables<<<256, 256, 0, stream>>>(emb, W0, b0, Walign, Wl, T0, Wpk);

  dim3 gscan(NC / 4, B_);
  // layer 0: table lookups + chunked scan
  scanA_l0<<<gscan, 256, 0, stream>>>(x, T0, cAB);
  scanB<<<B_, 256, 0, stream>>>(cAB, cHin);
  scanC_l0<<<gscan, 256, 0, stream>>>(x, T0, cHin, h);

  // layer 1 (full)
  gemm_scanA<<<B_ * NC, 256, 0, stream>>>(h, Wpk, bl, gh, cAB, 0);
  scanB<<<B_, 256, 0, stream>>>(cAB, cHin);
  scanC_mid<<<gscan, 256, 0, stream>>>(gh, cHin, h, 0);

  // layer 2: only the last 4 chunks of gh / h are ever consumed downstream
  gemm_scanA<<<B_ * NC, 256, 0, stream>>>(h, Wpk + (size_t)GH * H_, bl + GH, gh, cAB, NC - 4);
  scanB<<<B_, 256, 0, stream>>>(cAB, cHin);
  scanC_mid<<<dim3(1, B_), 256, 0, stream>>>(gh, cHin, h, NC - 4);

  out_logits<<<B_ * NM_, 256, 0, stream>>>(h, Wout, bout, (float*)d_out);
}